// Round 10
// baseline (445.904 us; speedup 1.0000x reference)
//
#include <hip/hip_runtime.h>
#include <math.h>

#define NN 30000
#define NE 480000
#define TPB 256
#define ETPB 64

// ---- CSR-path workspace layout (float offsets) ----
#define NG_OFF    0           // 600000 g vectors (Wd folded)
#define NW1K_OFF  600000      // 512
#define NW1V_OFF  600512      // 512
#define NW2K_OFF  601024      // 9216
#define NW2V_OFF  610240      // 9216
#define NCNT_OFF  619456      // 30000 int
#define NC2_OFF   649456      // 30000 int
#define NZ_OFF    679456      // 30000 f32
#define NBASE_OFF 709456      // 8 int
#define NOFF_OFF  709464      // 30000 int
#define NEVS_OFF  739464      // 480000 f32
#define NVSC_OFF  1219464     // 9600000 halfs
#define NTOT      6019464     // floats (~24.1 MB)

#define INV_SQRT8  0.35355339059327376f
#define SIG_SS     0.02209708691207961f
#define SIG_UU     0.01804219591217582f
#define SIG_SU     0.02209708691207961f
#define SIG_US     0.03125f
#define D0S        0.08838834764831845f
#define D1S        0.10206207261596575f

// single-wave DS ordering pin (r13-verified)
#define WBAR() __builtin_amdgcn_wave_barrier()

typedef _Float16 half2v __attribute__((ext_vector_type(2)));
typedef _Float16 f16x4  __attribute__((ext_vector_type(4)));
typedef _Float16 f16x8  __attribute__((ext_vector_type(8)));
typedef float    f32x4  __attribute__((ext_vector_type(4)));

// async global->LDS, 16B per lane; LDS dest = uniform base + lane*16 (HW rule)
#define GLD_LDS(gsrc, ldst) \
    __builtin_amdgcn_global_load_lds( \
        (const __attribute__((address_space(1))) void*)(gsrc), \
        (__attribute__((address_space(3))) void*)(ldst), 16, 0, 0)

__device__ __forceinline__ float fdot2(half2v a, half2v b, float c) {
    return __builtin_amdgcn_fdot2(a, b, c, false);
}

// ---------- fused prep: weight pack (0..17) + g vectors (18..135) + edge hist (136..)
__global__ __launch_bounds__(TPB) void prep_all(
    const float* __restrict__ x, const int* __restrict__ ei,
    const float* __restrict__ wq0, const float* __restrict__ wq1,
    const float* __restrict__ wk1, const float* __restrict__ wk2,
    const float* __restrict__ wv1, const float* __restrict__ wv2,
    const float* __restrict__ wd0, const float* __restrict__ wd1,
    half2v* __restrict__ w1pk, half2v* __restrict__ w1pv,
    _Float16* __restrict__ w2fk, _Float16* __restrict__ w2fv,
    float* __restrict__ g, int* __restrict__ cnt)
{
    const int b = blockIdx.x;
    if (b < 18) {
        int tid = b * TPB + threadIdx.x;   // 4608 exactly
        {
            int p = tid / 2304, rem = tid % 2304;
            int fg = rem >> 6, l = rem & 63;
            int t = fg >> 1, s = fg & 1;
            int kbase = s * 32 + (l >> 4) * 8;
            int m = t * 16 + (l & 15);
            float sig = (m < 128) ? SIG_SS : (m < 192) ? SIG_UU
                      : (m < 256) ? SIG_SU : SIG_US;
            const float* W2 = p ? wv2 : wk2;
            _Float16* dst = (p ? w2fv : w2fk) + (size_t)(fg * 64 + l) * 8;
#pragma unroll
            for (int jj = 0; jj < 8; ++jj)
                dst[jj] = (_Float16)(W2[(size_t)(kbase + jj) * 288 + m] * sig);
        }
        if (tid < 512) {
            int hh = tid >> 3, a2 = tid & 7;
            w1pk[tid] = half2v{(_Float16)(wk1[(2 * a2) * 64 + hh] * 0.25f),
                               (_Float16)(wk1[(2 * a2 + 1) * 64 + hh] * 0.25f)};
            w1pv[tid] = half2v{(_Float16)(wv1[(2 * a2) * 64 + hh] * 0.25f),
                               (_Float16)(wv1[(2 * a2 + 1) * 64 + hh] * 0.25f)};
        }
    } else if (b < 136) {
        // ---- per-node g = Wd-folded q (r12-verified) ----
        int n = (b - 18) * TPB + threadIdx.x;
        if (n >= NN) return;
        const float* xr = x + (size_t)n * 40;
        float* o = g + (size_t)n * 20;
        float q0[8];
#pragma unroll
        for (int bb = 0; bb < 8; ++bb) {
            float acc = 0.f;
#pragma unroll
            for (int a = 0; a < 16; ++a) acc += xr[a] * wq0[a * 8 + bb];
            q0[bb] = acc * 0.25f;
        }
#pragma unroll
        for (int bb = 0; bb < 8; ++bb) {
            float acc = 0.f;
#pragma unroll
            for (int a = 0; a < 8; ++a) acc += q0[a] * wd0[a * 8 + bb];
            o[bb] = acc * D0S;
        }
        float q1[4][3];
#pragma unroll
        for (int bb = 0; bb < 4; ++bb)
#pragma unroll
            for (int c = 0; c < 3; ++c) {
                float acc = 0.f;
#pragma unroll
                for (int a = 0; a < 8; ++a) acc += xr[16 + a * 3 + c] * wq1[a * 4 + bb];
                q1[bb][c] = acc * INV_SQRT8;
            }
#pragma unroll
        for (int bb = 0; bb < 4; ++bb)
#pragma unroll
            for (int c = 0; c < 3; ++c) {
                float acc = 0.f;
#pragma unroll
                for (int a = 0; a < 4; ++a) acc += q1[a][c] * wd1[a * 4 + bb];
                o[8 + bb * 3 + c] = acc * D1S;
            }
    } else {
        // ---- edge histogram (cnt pre-zeroed by memset) ----
        int e = (b - 136) * TPB + threadIdx.x;   // 1875 blocks, exact
        atomicAdd(cnt + ei[NE + e], 1);
    }
}

// ---------- parallel order-free scan: block-local prefix + atomic base ----------
__global__ __launch_bounds__(TPB) void scan_blk(const int* __restrict__ cnt,
                                                int* __restrict__ offs,
                                                int* __restrict__ base)
{
    __shared__ int sdata[TPB];
    __shared__ int bbase;
    const int t = threadIdx.x;
    const int idx = blockIdx.x * TPB + t;
    const int v = (idx < NN) ? cnt[idx] : 0;
    sdata[t] = v;
    __syncthreads();
    for (int off = 1; off < TPB; off <<= 1) {
        int u = (t >= off) ? sdata[t - off] : 0;
        __syncthreads();
        sdata[t] += u;
        __syncthreads();
    }
    if (t == TPB - 1) bbase = atomicAdd(base, sdata[TPB - 1]);
    __syncthreads();
    if (idx < NN) offs[idx] = bbase + sdata[t] - v;   // exclusive within block
}

// ---------- fused k+v edge kernel: LDS A-staging (r24) ----------
// r19-r23 mapped the bottleneck: the 72 A-stream global loads/block (74KB,
// > L1, L2-latency-bound, shallow pipelining) ARE the 204us. r23 proved more
// waves with fewer regs doesn't help. Fix the stall at the source: bulk
// async-stage each GEMM's 36KB A-stream into LDS (36 global_load_lds of
// 16B/lane), issued a full phase early:
//   stage-K after h-MLP -> vmcnt(0) -> K-GEMM reads ds_read_b128
//   lgkmcnt(0) fence -> stage-V (latency hides under k-epilogue)
//   -> vmcnt(0) -> V-GEMM.
// Manual waits only at the two buffer-alias points (+sched_barrier, rule18);
// all other loads keep compiler-counted waits. LDS 46.3KB -> 3 blk/CU:
// deliberate occupancy sacrifice (9%) for near-stall-free waves. (64,1):
// LDS is the binder, no reg cap. Falsifier: edge >= 204us -> latency model
// wrong -> pivot to 32-edge A-amortization.
__global__ __launch_bounds__(ETPB, 1) void edge_fused(
    const float* __restrict__ x, const int* __restrict__ ei,
    const float* __restrict__ eattr, const float* __restrict__ emb,
    const float* __restrict__ el,
    const half2v* __restrict__ w1pk, const f16x8* __restrict__ w2fk,
    const half2v* __restrict__ w1pv, const f16x8* __restrict__ w2fv,
    const float* __restrict__ gn, const int* __restrict__ offs,
    int* __restrict__ c2, float* __restrict__ Z,
    float* __restrict__ evs, _Float16* __restrict__ vsc)
{
    __shared__ f16x8 sh_A[36][64];                    // staged A stream (36864 B)
    __shared__ __align__(16) _Float16 sh_R[16][296];  // R dumps (9472 B)

    const int l = threadIdx.x;            // single wave
    const int q = l >> 4, n = l & 15;
    const int e = blockIdx.x * 16 + n;
    const int i = ei[e];
    const int j = ei[NE + e];
    const float4 ea = *(const float4*)(eattr + (size_t)e * 4);
    const float y0 = ea.x, y1x = ea.y, y1y = ea.z, y1z = ea.w;
    const float len = el[e];

    // in-kernel rank (CSR slot); latency hides under h-MLP
    int pe0 = 0;
    if (l < 16) pe0 = offs[j] + atomicAdd(c2 + j, 1);

    // ---- both hidden layers; B fragments register-resident ----
    // thread (q,n) computes k in {8q..8q+7} (B0) / {32+8q..+7} (B1) =
    // the 16x16x32 MFMA B-lane-layout for lane l = 16q+n (r16+-verified).
    f16x8 Bk0, Bk1, Bv0, Bv1;
    {
        half2v em2[8];
        const float4* ep = (const float4*)(emb + (size_t)e * 16);
#pragma unroll
        for (int p = 0; p < 4; ++p) {
            float4 v = ep[p];
            em2[2 * p]     = half2v{(_Float16)v.x, (_Float16)v.y};
            em2[2 * p + 1] = half2v{(_Float16)v.z, (_Float16)v.w};
        }
#pragma unroll
        for (int hf = 0; hf < 2; ++hf) {
            f16x8 hk, hv;
#pragma unroll
            for (int ii = 0; ii < 8; ++ii) {
                const int k = hf * 32 + q * 8 + ii;
                const half2v* wrk = w1pk + (size_t)k * 8;
                const half2v* wrv = w1pv + (size_t)k * 8;
                float a0 = 0.f, a1 = 0.f, c0 = 0.f, c1 = 0.f;
#pragma unroll
                for (int a2 = 0; a2 < 4; ++a2) {
                    a0 = fdot2(em2[2 * a2],     wrk[2 * a2],     a0);
                    a1 = fdot2(em2[2 * a2 + 1], wrk[2 * a2 + 1], a1);
                    c0 = fdot2(em2[2 * a2],     wrv[2 * a2],     c0);
                    c1 = fdot2(em2[2 * a2 + 1], wrv[2 * a2 + 1], c1);
                }
                const float zk = a0 + a1, zv = c0 + c1;
                hk[ii] = (_Float16)(zk * __builtin_amdgcn_rcpf(1.f + __expf(-zk)));
                hv[ii] = (_Float16)(zv * __builtin_amdgcn_rcpf(1.f + __expf(-zv)));
            }
            if (hf == 0) { Bk0 = hk; Bv0 = hv; } else { Bk1 = hk; Bv1 = hv; }
        }
    }

    // ---- this thread's x-slice: s-channels [4q,4q+4), u-channels [2q,2q+2) ----
    float xs[4];
    float xu[2][3];
    {
        const float* xb = x + (size_t)i * 40;
        float4 s4 = *(const float4*)(xb + 4 * q);
        xs[0] = s4.x; xs[1] = s4.y; xs[2] = s4.z; xs[3] = s4.w;
        const float* ub = xb + 16 + 6 * q;
        float2 u0 = *(const float2*)(ub);
        float2 u1 = *(const float2*)(ub + 2);
        float2 u2 = *(const float2*)(ub + 4);
        xu[0][0] = u0.x; xu[0][1] = u0.y; xu[0][2] = u1.x;
        xu[1][0] = u1.y; xu[1][1] = u2.x; xu[1][2] = u2.y;
    }

    // partial-tensor-product (r21 low-liveness form)
    auto P_COMPUTE = [&](float P0[8], float P1[4][3]) {
#pragma unroll
        for (int b = 0; b < 8; ++b) P0[b] = 0.f;
#pragma unroll
        for (int d = 0; d < 4; ++d) {
            const f16x8 rv = *(const f16x8*)&sh_R[n][(4 * q + d) * 8];
            const float xv = xs[d];
#pragma unroll
            for (int b = 0; b < 8; ++b) P0[b] += xv * (float)rv[b];
        }
#pragma unroll
        for (int b = 0; b < 8; ++b) P0[b] *= y0;
#pragma unroll
        for (int d = 0; d < 2; ++d) {
            const f16x8 rv = *(const f16x8*)&sh_R[n][128 + (2 * q + d) * 8];
            const float xy = xu[d][0] * y1x + xu[d][1] * y1y + xu[d][2] * y1z;
#pragma unroll
            for (int b = 0; b < 8; ++b) P0[b] += xy * (float)rv[b];
        }
        {
            float su[4] = {0.f, 0.f, 0.f, 0.f};
#pragma unroll
            for (int d = 0; d < 4; ++d) {
                const f16x4 rv = *(const f16x4*)&sh_R[n][192 + (4 * q + d) * 4];
                const float xv = xs[d];
#pragma unroll
                for (int b = 0; b < 4; ++b) su[b] += xv * (float)rv[b];
            }
#pragma unroll
            for (int b = 0; b < 4; ++b) {
                P1[b][0] = su[b] * y1x;
                P1[b][1] = su[b] * y1y;
                P1[b][2] = su[b] * y1z;
            }
        }
#pragma unroll
        for (int d = 0; d < 2; ++d) {
            const f16x4 rv = *(const f16x4*)&sh_R[n][256 + (2 * q + d) * 4];
#pragma unroll
            for (int b = 0; b < 4; ++b) {
                const float wv = y0 * (float)rv[b];
                P1[b][0] += xu[d][0] * wv;
                P1[b][1] += xu[d][1] * wv;
                P1[b][2] += xu[d][2] * wv;
            }
        }
    };

    // ---- stage K A-stream (bulk async; issued after h-MLP's VMEM) ----
    __builtin_amdgcn_sched_barrier(0);
#pragma unroll
    for (int r = 0; r < 36; ++r)
        GLD_LDS(w2fk + r * 64 + l, &sh_A[r][0]);
    __builtin_amdgcn_sched_barrier(0);
    asm volatile("s_waitcnt vmcnt(0)" ::: "memory");
    __builtin_amdgcn_sched_barrier(0);

    // ================= K GEMM (A from LDS; acc scoped per tile) =============
    {
#pragma unroll
        for (int t = 0; t < 18; ++t) {
            f16x8 A0 = sh_A[2 * t][l];
            f16x8 A1 = sh_A[2 * t + 1][l];
            f32x4 acc = f32x4{0.f, 0.f, 0.f, 0.f};
            acc = __builtin_amdgcn_mfma_f32_16x16x32_f16(A0, Bk0, acc, 0, 0, 0);
            acc = __builtin_amdgcn_mfma_f32_16x16x32_f16(A1, Bk1, acc, 0, 0, 0);
            f16x4 rv = {(_Float16)acc[0], (_Float16)acc[1],
                        (_Float16)acc[2], (_Float16)acc[3]};
            *(f16x4*)&sh_R[n][t * 16 + 4 * q] = rv;
        }
    }
    WBAR();

    // ---- drain sh_A ds_reads, then stage V into the SAME buffer ----
    asm volatile("s_waitcnt lgkmcnt(0)" ::: "memory");
    __builtin_amdgcn_sched_barrier(0);
#pragma unroll
    for (int r = 0; r < 36; ++r)
        GLD_LDS(w2fv + r * 64 + l, &sh_A[r][0]);
    __builtin_amdgcn_sched_barrier(0);

    // ---- k epilogue (covers stage-V latency): score, evs, Z ----
    {
        float P0[8], P1[4][3];
        P_COMPUTE(P0, P1);
        const float* gj = gn + (size_t)j * 20;
        float pd = 0.f;
        {
            float4 ga = *(const float4*)(gj);
            float4 gb = *(const float4*)(gj + 4);
            pd += P0[0] * ga.x + P0[1] * ga.y + P0[2] * ga.z + P0[3] * ga.w;
            pd += P0[4] * gb.x + P0[5] * gb.y + P0[6] * gb.z + P0[7] * gb.w;
        }
        {
            float4 ga = *(const float4*)(gj + 8);
            float4 gb = *(const float4*)(gj + 12);
            float4 gc = *(const float4*)(gj + 16);
            pd += P1[0][0] * ga.x + P1[0][1] * ga.y + P1[0][2] * ga.z
                + P1[1][0] * ga.w;
            pd += P1[1][1] * gb.x + P1[1][2] * gb.y + P1[2][0] * gb.z
                + P1[2][1] * gb.w;
            pd += P1[2][2] * gc.x + P1[3][0] * gc.y + P1[3][1] * gc.z
                + P1[3][2] * gc.w;
        }
        pd += __shfl_xor(pd, 16);
        pd += __shfl_xor(pd, 32);
        if (l < 16) {
            const float tt = 10.f * (1.f - len / 3.15f);
            float cut = 0.f;
            if (tt > 0.f) cut = __expf(-1.f / fmaxf(tt, 1e-6f));
            const float ev = cut * __expf(pd);
            evs[pe0] = ev;
            atomicAdd(Z + j, ev);
        }
    }
    WBAR();   // k-epilogue sh_R reads precede V dump (in-order DS)

    // ---- stage-V landed? ----
    asm volatile("s_waitcnt vmcnt(0)" ::: "memory");
    __builtin_amdgcn_sched_barrier(0);

    // ================= V GEMM (A from LDS; acc scoped per tile) =============
    {
#pragma unroll
        for (int t = 0; t < 18; ++t) {
            f16x8 A0 = sh_A[2 * t][l];
            f16x8 A1 = sh_A[2 * t + 1][l];
            f32x4 acc = f32x4{0.f, 0.f, 0.f, 0.f};
            acc = __builtin_amdgcn_mfma_f32_16x16x32_f16(A0, Bv0, acc, 0, 0, 0);
            acc = __builtin_amdgcn_mfma_f32_16x16x32_f16(A1, Bv1, acc, 0, 0, 0);
            f16x4 rv = {(_Float16)acc[0], (_Float16)acc[1],
                        (_Float16)acc[2], (_Float16)acc[3]};
            *(f16x4*)&sh_R[n][t * 16 + 4 * q] = rv;
        }
    }
    WBAR();

    // ---- v epilogue: partials -> 20-value cross-q reduce -> q==0 stores ----
    {
        float P0[8], P1[4][3];
        P_COMPUTE(P0, P1);
#pragma unroll
        for (int b = 0; b < 8; ++b) {
            P0[b] += __shfl_xor(P0[b], 16);
            P0[b] += __shfl_xor(P0[b], 32);
        }
#pragma unroll
        for (int b = 0; b < 4; ++b)
#pragma unroll
            for (int c = 0; c < 3; ++c) {
                P1[b][c] += __shfl_xor(P1[b][c], 16);
                P1[b][c] += __shfl_xor(P1[b][c], 32);
            }
        if (l < 16) {
            _Float16* rec = vsc + (size_t)pe0 * 20;   // 40B records
            f16x4 o0 = {(_Float16)P0[0], (_Float16)P0[1],
                        (_Float16)P0[2], (_Float16)P0[3]};
            f16x4 o1 = {(_Float16)P0[4], (_Float16)P0[5],
                        (_Float16)P0[6], (_Float16)P0[7]};
            f16x4 o2 = {(_Float16)P1[0][0], (_Float16)P1[0][1],
                        (_Float16)P1[0][2], (_Float16)P1[1][0]};
            f16x4 o3 = {(_Float16)P1[1][1], (_Float16)P1[1][2],
                        (_Float16)P1[2][0], (_Float16)P1[2][1]};
            f16x4 o4 = {(_Float16)P1[2][2], (_Float16)P1[3][0],
                        (_Float16)P1[3][1], (_Float16)P1[3][2]};
            *(f16x4*)&rec[0]  = o0;
            *(f16x4*)&rec[4]  = o1;
            *(f16x4*)&rec[8]  = o2;
            *(f16x4*)&rec[12] = o3;
            *(f16x4*)&rec[16] = o4;
        }
    }
}

// ---------- node gather: Z precomputed; single weighted pass, zero atomics ----------
__global__ __launch_bounds__(TPB) void node_gather(
    const int* __restrict__ offs, const int* __restrict__ cntp,
    const float* __restrict__ Z,
    const float* __restrict__ evs, const _Float16* __restrict__ vsc,
    float* __restrict__ out)
{
    const int wv = threadIdx.x >> 6, lane = threadIdx.x & 63;
    const int j = blockIdx.x * 4 + wv;
    if (j >= NN) return;
    const int o0 = offs[j], cnt = cntp[j];
    const float zz = Z[j];
    const float invZ = (zz > 0.f) ? (1.f / zz) : 0.f;

    const int g = lane / 20, c = lane % 20;
    float acc = 0.f;
    if (g < 3) {
        for (int t = g; t < cnt; t += 3) {
            const float ev = evs[o0 + t];
            const float wgt = sqrtf(fmaxf(ev * invZ, 0.f));
            acc += wgt * (float)vsc[(size_t)(o0 + t) * 20 + c];
        }
    }
    const float a1 = __shfl(acc, lane + 20);
    const float a2 = __shfl(acc, lane + 40);
    if (lane < 20) out[(size_t)j * 20 + lane] = acc + a1 + a2;
}

extern "C" void kernel_launch(void* const* d_in, const int* in_sizes, int n_in,
                              void* d_out, int out_size, void* d_ws, size_t ws_size,
                              hipStream_t stream)
{
    const float* x     = (const float*)d_in[0];
    const int*   eidx  = (const int*)d_in[1];
    const float* eattr = (const float*)d_in[2];
    const float* emb   = (const float*)d_in[3];
    const float* elen  = (const float*)d_in[4];
    const float* wq0   = (const float*)d_in[5];
    const float* wq1   = (const float*)d_in[6];
    const float* wk1   = (const float*)d_in[7];
    const float* wk2   = (const float*)d_in[8];
    const float* wv1   = (const float*)d_in[9];
    const float* wv2   = (const float*)d_in[10];
    const float* wd0   = (const float*)d_in[11];
    const float* wd1   = (const float*)d_in[12];

    float* ws  = (float*)d_ws;
    float* out = (float*)d_out;

    half2v* w1pk = (half2v*)(ws + NW1K_OFF);
    half2v* w1pv = (half2v*)(ws + NW1V_OFF);
    _Float16* w2fk = (_Float16*)(ws + NW2K_OFF);
    _Float16* w2fv = (_Float16*)(ws + NW2V_OFF);
    int* cnt  = (int*)(ws + NCNT_OFF);
    int* c2   = (int*)(ws + NC2_OFF);
    float* Z  = ws + NZ_OFF;
    int* base = (int*)(ws + NBASE_OFF);
    int* offs = (int*)(ws + NOFF_OFF);
    float* evs = ws + NEVS_OFF;
    _Float16* vsc = (_Float16*)(ws + NVSC_OFF);

    // zero cnt + c2 + Z + base (contiguous) in one memset
    hipMemsetAsync(cnt, 0, (3 * NN + 8) * sizeof(int), stream);

    // prep: weights + g + histogram (1875 hist blocks)
    prep_all<<<136 + NE / TPB, TPB, 0, stream>>>(
        x, eidx, wq0, wq1, wk1, wk2, wv1, wv2, wd0, wd1,
        w1pk, w1pv, w2fk, w2fv, ws + NG_OFF, cnt);

    scan_blk<<<(NN + TPB - 1) / TPB, TPB, 0, stream>>>(cnt, offs, base);

    edge_fused<<<NE / 16, ETPB, 0, stream>>>(
        x, eidx, eattr, emb, elen,
        w1pk, (const f16x8*)w2fk, w1pv, (const f16x8*)w2fv,
        ws + NG_OFF, offs, c2, Z, evs, vsc);

    node_gather<<<(NN + 3) / 4, TPB, 0, stream>>>(offs, cnt, Z, evs, vsc, out);
}

// Round 12
// 268.866 us; speedup vs baseline: 1.6585x; 1.6585x over previous
//
#include <hip/hip_runtime.h>
#include <math.h>

#define NN 30000
#define NE 480000
#define TPB 256
#define ETPB 64

// ---- CSR-path workspace layout (float offsets) ----
#define NG_OFF    0           // 600000 g vectors (Wd folded)
#define NW1K_OFF  600000      // 512 floats = 2048B: 256 f16x4 W1-K MFMA A-frags
#define NW1V_OFF  600512      // 512 floats = 2048B: 256 f16x4 W1-V MFMA A-frags
#define NW2K_OFF  601024      // 9216
#define NW2V_OFF  610240      // 9216
#define NCNT_OFF  619456      // 30000 int
#define NC2_OFF   649456      // 30000 int
#define NZ_OFF    679456      // 30000 f32
#define NBASE_OFF 709456      // 8 int
#define NOFF_OFF  709464      // 30000 int
#define NEVS_OFF  739464      // 480000 f32
#define NVSC_OFF  1219464     // 9600000 halfs
#define NTOT      6019464     // floats (~24.1 MB)

#define INV_SQRT8  0.35355339059327376f
#define SIG_SS     0.02209708691207961f
#define SIG_UU     0.01804219591217582f
#define SIG_SU     0.02209708691207961f
#define SIG_US     0.03125f
#define D0S        0.08838834764831845f
#define D1S        0.10206207261596575f

// single-wave DS ordering pin (r13-verified)
#define WBAR() __builtin_amdgcn_wave_barrier()

typedef _Float16 half2v __attribute__((ext_vector_type(2)));
typedef _Float16 f16x4  __attribute__((ext_vector_type(4)));
typedef _Float16 f16x8  __attribute__((ext_vector_type(8)));
typedef float    f32x4  __attribute__((ext_vector_type(4)));

// ---------- fused prep: weight pack (0..17) + g vectors (18..135) + edge hist (136..)
__global__ __launch_bounds__(TPB) void prep_all(
    const float* __restrict__ x, const int* __restrict__ ei,
    const float* __restrict__ wq0, const float* __restrict__ wq1,
    const float* __restrict__ wk1, const float* __restrict__ wk2,
    const float* __restrict__ wv1, const float* __restrict__ wv2,
    const float* __restrict__ wd0, const float* __restrict__ wd1,
    f16x4* __restrict__ w1pk, f16x4* __restrict__ w1pv,
    _Float16* __restrict__ w2fk, _Float16* __restrict__ w2fv,
    float* __restrict__ g, int* __restrict__ cnt)
{
    const int b = blockIdx.x;
    if (b < 18) {
        int tid = b * TPB + threadIdx.x;   // 4608 exactly
        {
            int p = tid / 2304, rem = tid % 2304;
            int fg = rem >> 6, l = rem & 63;
            int t = fg >> 1, s = fg & 1;
            int kbase = s * 32 + (l >> 4) * 8;
            int m = t * 16 + (l & 15);
            float sig = (m < 128) ? SIG_SS : (m < 192) ? SIG_UU
                      : (m < 256) ? SIG_SU : SIG_US;
            const float* W2 = p ? wv2 : wk2;
            _Float16* dst = (p ? w2fv : w2fk) + (size_t)(fg * 64 + l) * 8;
#pragma unroll
            for (int jj = 0; jj < 8; ++jj)
                dst[jj] = (_Float16)(W2[(size_t)(kbase + jj) * 288 + m] * sig);
        }
        // W1 MFMA A-frag pack (r25): 16x16x16 f16 A[m][k], m=lane&15, k=4q+i.
        // tile t: frag[t*64+l][i] = W1[a=4q+i][h=16t+n] * 0.25
        if (tid < 256) {
            int t = tid >> 6, ll = tid & 63;
            int qq = ll >> 4, nn = ll & 15;
            int hh = 16 * t + nn;
            f16x4 pk, pv;
#pragma unroll
            for (int i2 = 0; i2 < 4; ++i2) {
                pk[i2] = (_Float16)(wk1[(4 * qq + i2) * 64 + hh] * 0.25f);
                pv[i2] = (_Float16)(wv1[(4 * qq + i2) * 64 + hh] * 0.25f);
            }
            w1pk[tid] = pk;
            w1pv[tid] = pv;
        }
    } else if (b < 136) {
        // ---- per-node g = Wd-folded q (r12-verified) ----
        int n = (b - 18) * TPB + threadIdx.x;
        if (n >= NN) return;
        const float* xr = x + (size_t)n * 40;
        float* o = g + (size_t)n * 20;
        float q0[8];
#pragma unroll
        for (int bb = 0; bb < 8; ++bb) {
            float acc = 0.f;
#pragma unroll
            for (int a = 0; a < 16; ++a) acc += xr[a] * wq0[a * 8 + bb];
            q0[bb] = acc * 0.25f;
        }
#pragma unroll
        for (int bb = 0; bb < 8; ++bb) {
            float acc = 0.f;
#pragma unroll
            for (int a = 0; a < 8; ++a) acc += q0[a] * wd0[a * 8 + bb];
            o[bb] = acc * D0S;
        }
        float q1[4][3];
#pragma unroll
        for (int bb = 0; bb < 4; ++bb)
#pragma unroll
            for (int c = 0; c < 3; ++c) {
                float acc = 0.f;
#pragma unroll
                for (int a = 0; a < 8; ++a) acc += xr[16 + a * 3 + c] * wq1[a * 4 + bb];
                q1[bb][c] = acc * INV_SQRT8;
            }
#pragma unroll
        for (int bb = 0; bb < 4; ++bb)
#pragma unroll
            for (int c = 0; c < 3; ++c) {
                float acc = 0.f;
#pragma unroll
                for (int a = 0; a < 4; ++a) acc += q1[a][c] * wd1[a * 4 + bb];
                o[8 + bb * 3 + c] = acc * D1S;
            }
    } else {
        // ---- edge histogram (cnt pre-zeroed by memset) ----
        int e = (b - 136) * TPB + threadIdx.x;   // 1875 blocks, exact
        atomicAdd(cnt + ei[NE + e], 1);
    }
}

// ---------- parallel order-free scan: block-local prefix + atomic base ----------
__global__ __launch_bounds__(TPB) void scan_blk(const int* __restrict__ cnt,
                                                int* __restrict__ offs,
                                                int* __restrict__ base)
{
    __shared__ int sdata[TPB];
    __shared__ int bbase;
    const int t = threadIdx.x;
    const int idx = blockIdx.x * TPB + t;
    const int v = (idx < NN) ? cnt[idx] : 0;
    sdata[t] = v;
    __syncthreads();
    for (int off = 1; off < TPB; off <<= 1) {
        int u = (t >= off) ? sdata[t - off] : 0;
        __syncthreads();
        sdata[t] += u;
        __syncthreads();
    }
    if (t == TPB - 1) bbase = atomicAdd(base, sdata[TPB - 1]);
    __syncthreads();
    if (idx < NN) offs[idx] = bbase + sdata[t] - v;   // exclusive within block
}

// ---------- fused k+v edge kernel: MFMA h-MLP (r25b; r25 + builtin-name fix) ----------
// r19-r24 invariant: dur ~ 60us-equiv VALU work / VALUBusy, VALUBusy peaks
// ~31% at r19's (64,2) high-ILP point; concurrency moves all lost. So cut
// the WORK: h=silu(emb@W1) was 256 fdot2/thread (~30% of VALU) — it is a
// [16e x 16NB]x[16NB x 64H] GEMM = 4x mfma_f32_16x16x16f16 per path on the
// 94%-idle MFMA pipe. B-frag = 4 emb floats/lane (emb traffic /4), A-frag =
// W1 repacked in prep. D: lane(q,n) holds h[16t+4q+r][edge n] -> ds_write
// sh_R[n][t*16+4q] -> ds_read std B-frags {8q..}+{32+8q..}. In-order DS +
// WBAR (r13 discipline); sh_R[0..64) later overwritten by K GEMM dump =
// safe in program order. Body/launch = r19/r22 proven (64,2).
// Falsifier: edge >= 204us or WRITE > 150MB -> revert r19 as final.
__global__ __launch_bounds__(ETPB, 2) void edge_fused(
    const float* __restrict__ x, const int* __restrict__ ei,
    const float* __restrict__ eattr, const float* __restrict__ emb,
    const float* __restrict__ el,
    const f16x4* __restrict__ w1pk, const f16x8* __restrict__ w2fk,
    const f16x4* __restrict__ w1pv, const f16x8* __restrict__ w2fv,
    const float* __restrict__ gn, const int* __restrict__ offs,
    int* __restrict__ c2, float* __restrict__ Z,
    float* __restrict__ evs, _Float16* __restrict__ vsc)
{
    __shared__ __align__(16) _Float16 sh_R[16][296];  // h stage + R dumps (9472 B)

    const int l = threadIdx.x;            // single wave
    const int q = l >> 4, n = l & 15;
    const int e = blockIdx.x * 16 + n;
    const int i = ei[e];
    const int j = ei[NE + e];
    const float4 ea = *(const float4*)(eattr + (size_t)e * 4);
    const float y0 = ea.x, y1x = ea.y, y1y = ea.z, y1z = ea.w;
    const float len = el[e];

    // in-kernel rank (CSR slot); latency hides under h phase
    int pe0 = 0;
    if (l < 16) pe0 = offs[j] + atomicAdd(c2 + j, 1);

    // ---- h-MLP via MFMA; B fragments land register-resident ----
    f16x8 Bk0, Bk1, Bv0, Bv1;
    {
        f16x4 Bemb;
        {
            float4 v = *(const float4*)(emb + (size_t)e * 16 + 4 * q);
            Bemb = f16x4{(_Float16)v.x, (_Float16)v.y,
                         (_Float16)v.z, (_Float16)v.w};
        }
        const f32x4 zero = f32x4{0.f, 0.f, 0.f, 0.f};
        // K path: 4 tiles of h[16t..16t+15][e]; lane holds rows 4q..4q+3
#pragma unroll
        for (int t = 0; t < 4; ++t) {
            f32x4 acc = __builtin_amdgcn_mfma_f32_16x16x16f16(
                w1pk[t * 64 + l], Bemb, zero, 0, 0, 0);
            f16x4 h4;
#pragma unroll
            for (int r = 0; r < 4; ++r) {
                const float z = acc[r];
                h4[r] = (_Float16)(z * __builtin_amdgcn_rcpf(1.f + __expf(-z)));
            }
            *(f16x4*)&sh_R[n][t * 16 + 4 * q] = h4;
        }
        WBAR();
        Bk0 = *(const f16x8*)&sh_R[n][8 * q];        // k in {8q..8q+7}
        Bk1 = *(const f16x8*)&sh_R[n][32 + 8 * q];   // k in {32+8q..+7}
        WBAR();   // Bk reads issued before h_v overwrites (in-order DS)
        // V path into the same staging area
#pragma unroll
        for (int t = 0; t < 4; ++t) {
            f32x4 acc = __builtin_amdgcn_mfma_f32_16x16x16f16(
                w1pv[t * 64 + l], Bemb, zero, 0, 0, 0);
            f16x4 h4;
#pragma unroll
            for (int r = 0; r < 4; ++r) {
                const float z = acc[r];
                h4[r] = (_Float16)(z * __builtin_amdgcn_rcpf(1.f + __expf(-z)));
            }
            *(f16x4*)&sh_R[n][t * 16 + 4 * q] = h4;
        }
        WBAR();
        Bv0 = *(const f16x8*)&sh_R[n][8 * q];
        Bv1 = *(const f16x8*)&sh_R[n][32 + 8 * q];
    }

    // ---- this thread's x-slice: s-channels [4q,4q+4), u-channels [2q,2q+2) ----
    float xs[4];
    float xu[2][3];
    {
        const float* xb = x + (size_t)i * 40;
        float4 s4 = *(const float4*)(xb + 4 * q);
        xs[0] = s4.x; xs[1] = s4.y; xs[2] = s4.z; xs[3] = s4.w;
        const float* ub = xb + 16 + 6 * q;
        float2 u0 = *(const float2*)(ub);
        float2 u1 = *(const float2*)(ub + 2);
        float2 u2 = *(const float2*)(ub + 4);
        xu[0][0] = u0.x; xu[0][1] = u0.y; xu[0][2] = u1.x;
        xu[1][0] = u1.y; xu[1][1] = u2.x; xu[1][2] = u2.y;
    }

    // partial-tensor-product (r21 low-liveness form)
    auto P_COMPUTE = [&](float P0[8], float P1[4][3]) {
#pragma unroll
        for (int b = 0; b < 8; ++b) P0[b] = 0.f;
#pragma unroll
        for (int d = 0; d < 4; ++d) {
            const f16x8 rv = *(const f16x8*)&sh_R[n][(4 * q + d) * 8];
            const float xv = xs[d];
#pragma unroll
            for (int b = 0; b < 8; ++b) P0[b] += xv * (float)rv[b];
        }
#pragma unroll
        for (int b = 0; b < 8; ++b) P0[b] *= y0;
#pragma unroll
        for (int d = 0; d < 2; ++d) {
            const f16x8 rv = *(const f16x8*)&sh_R[n][128 + (2 * q + d) * 8];
            const float xy = xu[d][0] * y1x + xu[d][1] * y1y + xu[d][2] * y1z;
#pragma unroll
            for (int b = 0; b < 8; ++b) P0[b] += xy * (float)rv[b];
        }
        {
            float su[4] = {0.f, 0.f, 0.f, 0.f};
#pragma unroll
            for (int d = 0; d < 4; ++d) {
                const f16x4 rv = *(const f16x4*)&sh_R[n][192 + (4 * q + d) * 4];
                const float xv = xs[d];
#pragma unroll
                for (int b = 0; b < 4; ++b) su[b] += xv * (float)rv[b];
            }
#pragma unroll
            for (int b = 0; b < 4; ++b) {
                P1[b][0] = su[b] * y1x;
                P1[b][1] = su[b] * y1y;
                P1[b][2] = su[b] * y1z;
            }
        }
#pragma unroll
        for (int d = 0; d < 2; ++d) {
            const f16x4 rv = *(const f16x4*)&sh_R[n][256 + (2 * q + d) * 4];
#pragma unroll
            for (int b = 0; b < 4; ++b) {
                const float wv = y0 * (float)rv[b];
                P1[b][0] += xu[d][0] * wv;
                P1[b][1] += xu[d][1] * wv;
                P1[b][2] += xu[d][2] * wv;
            }
        }
    };

    // ================= K GEMM (B from registers; acc scoped per tile) =======
    {
#pragma unroll
        for (int t = 0; t < 18; ++t) {
            f16x8 A0 = w2fk[(t * 2 + 0) * 64 + l];
            f16x8 A1 = w2fk[(t * 2 + 1) * 64 + l];
            f32x4 acc = f32x4{0.f, 0.f, 0.f, 0.f};
            acc = __builtin_amdgcn_mfma_f32_16x16x32_f16(A0, Bk0, acc, 0, 0, 0);
            acc = __builtin_amdgcn_mfma_f32_16x16x32_f16(A1, Bk1, acc, 0, 0, 0);
            f16x4 rv = {(_Float16)acc[0], (_Float16)acc[1],
                        (_Float16)acc[2], (_Float16)acc[3]};
            *(f16x4*)&sh_R[n][t * 16 + 4 * q] = rv;
        }
    }
    WBAR();

    // ---- k epilogue: score via partials, g streamed, scalar shfl reduce ----
    {
        float P0[8], P1[4][3];
        P_COMPUTE(P0, P1);
        const float* gj = gn + (size_t)j * 20;
        float pd = 0.f;
        {
            float4 ga = *(const float4*)(gj);
            float4 gb = *(const float4*)(gj + 4);
            pd += P0[0] * ga.x + P0[1] * ga.y + P0[2] * ga.z + P0[3] * ga.w;
            pd += P0[4] * gb.x + P0[5] * gb.y + P0[6] * gb.z + P0[7] * gb.w;
        }
        {
            float4 ga = *(const float4*)(gj + 8);
            float4 gb = *(const float4*)(gj + 12);
            float4 gc = *(const float4*)(gj + 16);
            pd += P1[0][0] * ga.x + P1[0][1] * ga.y + P1[0][2] * ga.z
                + P1[1][0] * ga.w;
            pd += P1[1][1] * gb.x + P1[1][2] * gb.y + P1[2][0] * gb.z
                + P1[2][1] * gb.w;
            pd += P1[2][2] * gc.x + P1[3][0] * gc.y + P1[3][1] * gc.z
                + P1[3][2] * gc.w;
        }
        pd += __shfl_xor(pd, 16);
        pd += __shfl_xor(pd, 32);
        if (l < 16) {
            const float tt = 10.f * (1.f - len / 3.15f);
            float cut = 0.f;
            if (tt > 0.f) cut = __expf(-1.f / fmaxf(tt, 1e-6f));
            const float ev = cut * __expf(pd);
            evs[pe0] = ev;
            atomicAdd(Z + j, ev);
        }
    }
    WBAR();   // k-epilogue sh_R reads precede V dump (in-order DS)

    // ================= V GEMM (B from registers; acc scoped per tile) =======
    {
#pragma unroll
        for (int t = 0; t < 18; ++t) {
            f16x8 A0 = w2fv[(t * 2 + 0) * 64 + l];
            f16x8 A1 = w2fv[(t * 2 + 1) * 64 + l];
            f32x4 acc = f32x4{0.f, 0.f, 0.f, 0.f};
            acc = __builtin_amdgcn_mfma_f32_16x16x32_f16(A0, Bv0, acc, 0, 0, 0);
            acc = __builtin_amdgcn_mfma_f32_16x16x32_f16(A1, Bv1, acc, 0, 0, 0);
            f16x4 rv = {(_Float16)acc[0], (_Float16)acc[1],
                        (_Float16)acc[2], (_Float16)acc[3]};
            *(f16x4*)&sh_R[n][t * 16 + 4 * q] = rv;
        }
    }
    WBAR();

    // ---- v epilogue: partials -> 20-value cross-q reduce -> q==0 stores ----
    {
        float P0[8], P1[4][3];
        P_COMPUTE(P0, P1);
#pragma unroll
        for (int b = 0; b < 8; ++b) {
            P0[b] += __shfl_xor(P0[b], 16);
            P0[b] += __shfl_xor(P0[b], 32);
        }
#pragma unroll
        for (int b = 0; b < 4; ++b)
#pragma unroll
            for (int c = 0; c < 3; ++c) {
                P1[b][c] += __shfl_xor(P1[b][c], 16);
                P1[b][c] += __shfl_xor(P1[b][c], 32);
            }
        if (l < 16) {
            _Float16* rec = vsc + (size_t)pe0 * 20;   // 40B records
            f16x4 o0 = {(_Float16)P0[0], (_Float16)P0[1],
                        (_Float16)P0[2], (_Float16)P0[3]};
            f16x4 o1 = {(_Float16)P0[4], (_Float16)P0[5],
                        (_Float16)P0[6], (_Float16)P0[7]};
            f16x4 o2 = {(_Float16)P1[0][0], (_Float16)P1[0][1],
                        (_Float16)P1[0][2], (_Float16)P1[1][0]};
            f16x4 o3 = {(_Float16)P1[1][1], (_Float16)P1[1][2],
                        (_Float16)P1[2][0], (_Float16)P1[2][1]};
            f16x4 o4 = {(_Float16)P1[2][2], (_Float16)P1[3][0],
                        (_Float16)P1[3][1], (_Float16)P1[3][2]};
            *(f16x4*)&rec[0]  = o0;
            *(f16x4*)&rec[4]  = o1;
            *(f16x4*)&rec[8]  = o2;
            *(f16x4*)&rec[12] = o3;
            *(f16x4*)&rec[16] = o4;
        }
    }
}

// ---------- node gather: Z precomputed; single weighted pass, zero atomics ----------
__global__ __launch_bounds__(TPB) void node_gather(
    const int* __restrict__ offs, const int* __restrict__ cntp,
    const float* __restrict__ Z,
    const float* __restrict__ evs, const _Float16* __restrict__ vsc,
    float* __restrict__ out)
{
    const int wv = threadIdx.x >> 6, lane = threadIdx.x & 63;
    const int j = blockIdx.x * 4 + wv;
    if (j >= NN) return;
    const int o0 = offs[j], cnt = cntp[j];
    const float zz = Z[j];
    const float invZ = (zz > 0.f) ? (1.f / zz) : 0.f;

    const int g = lane / 20, c = lane % 20;
    float acc = 0.f;
    if (g < 3) {
        for (int t = g; t < cnt; t += 3) {
            const float ev = evs[o0 + t];
            const float wgt = sqrtf(fmaxf(ev * invZ, 0.f));
            acc += wgt * (float)vsc[(size_t)(o0 + t) * 20 + c];
        }
    }
    const float a1 = __shfl(acc, lane + 20);
    const float a2 = __shfl(acc, lane + 40);
    if (lane < 20) out[(size_t)j * 20 + lane] = acc + a1 + a2;
}

extern "C" void kernel_launch(void* const* d_in, const int* in_sizes, int n_in,
                              void* d_out, int out_size, void* d_ws, size_t ws_size,
                              hipStream_t stream)
{
    const float* x     = (const float*)d_in[0];
    const int*   eidx  = (const int*)d_in[1];
    const float* eattr = (const float*)d_in[2];
    const float* emb   = (const float*)d_in[3];
    const float* elen  = (const float*)d_in[4];
    const float* wq0   = (const float*)d_in[5];
    const float* wq1   = (const float*)d_in[6];
    const float* wk1   = (const float*)d_in[7];
    const float* wk2   = (const float*)d_in[8];
    const float* wv1   = (const float*)d_in[9];
    const float* wv2   = (const float*)d_in[10];
    const float* wd0   = (const float*)d_in[11];
    const float* wd1   = (const float*)d_in[12];

    float* ws  = (float*)d_ws;
    float* out = (float*)d_out;

    f16x4* w1pk = (f16x4*)(ws + NW1K_OFF);
    f16x4* w1pv = (f16x4*)(ws + NW1V_OFF);
    _Float16* w2fk = (_Float16*)(ws + NW2K_OFF);
    _Float16* w2fv = (_Float16*)(ws + NW2V_OFF);
    int* cnt  = (int*)(ws + NCNT_OFF);
    int* c2   = (int*)(ws + NC2_OFF);
    float* Z  = ws + NZ_OFF;
    int* base = (int*)(ws + NBASE_OFF);
    int* offs = (int*)(ws + NOFF_OFF);
    float* evs = ws + NEVS_OFF;
    _Float16* vsc = (_Float16*)(ws + NVSC_OFF);

    // zero cnt + c2 + Z + base (contiguous) in one memset
    hipMemsetAsync(cnt, 0, (3 * NN + 8) * sizeof(int), stream);

    // prep: weights + g + histogram (1875 hist blocks)
    prep_all<<<136 + NE / TPB, TPB, 0, stream>>>(
        x, eidx, wq0, wq1, wk1, wk2, wv1, wv2, wd0, wd1,
        w1pk, w1pv, w2fk, w2fv, ws + NG_OFF, cnt);

    scan_blk<<<(NN + TPB - 1) / TPB, TPB, 0, stream>>>(cnt, offs, base);

    edge_fused<<<NE / 16, ETPB, 0, stream>>>(
        x, eidx, eattr, emb, elen,
        w1pk, (const f16x8*)w2fk, w1pv, (const f16x8*)w2fv,
        ws + NG_OFF, offs, c2, Z, evs, vsc);

    node_gather<<<(NN + 3) / 4, TPB, 0, stream>>>(offs, cnt, Z, evs, vsc, out);
}

// Round 13
// 267.905 us; speedup vs baseline: 1.6644x; 1.0036x over previous
//
#include <hip/hip_runtime.h>
#include <math.h>

#define NN 30000
#define NE 480000
#define TPB 256
#define ETPB 64

// ---- CSR-path workspace layout (float offsets) ----
#define NG_OFF    0           // 600000 g vectors (Wd folded)
#define NW1K_OFF  600000      // 512 floats = 2048B: 256 f16x4 W1-K MFMA A-frags
#define NW1V_OFF  600512      // 512 floats = 2048B: 256 f16x4 W1-V MFMA A-frags
#define NW2K_OFF  601024      // 9216
#define NW2V_OFF  610240      // 9216
#define NCNT_OFF  619456      // 30000 int
#define NC2_OFF   649456      // 30000 int
#define NZ_OFF    679456      // 30000 f32
#define NBASE_OFF 709456      // 8 int
#define NOFF_OFF  709464      // 30000 int
#define NEVS_OFF  739464      // 480000 f32
#define NVSC_OFF  1219464     // 9600000 halfs
#define NTOT      6019464     // floats (~24.1 MB)

#define INV_SQRT8  0.35355339059327376f
#define SIG_SS     0.02209708691207961f
#define SIG_UU     0.01804219591217582f
#define SIG_SU     0.02209708691207961f
#define SIG_US     0.03125f
#define D0S        0.08838834764831845f
#define D1S        0.10206207261596575f

// single-wave DS ordering pin (r13-verified)
#define WBAR() __builtin_amdgcn_wave_barrier()

typedef _Float16 half2v __attribute__((ext_vector_type(2)));
typedef _Float16 f16x4  __attribute__((ext_vector_type(4)));
typedef _Float16 f16x8  __attribute__((ext_vector_type(8)));
typedef float    f32x4  __attribute__((ext_vector_type(4)));

// ---------- fused prep: weight pack (0..17) + g vectors (18..135) + edge hist (136..)
__global__ __launch_bounds__(TPB) void prep_all(
    const float* __restrict__ x, const int* __restrict__ ei,
    const float* __restrict__ wq0, const float* __restrict__ wq1,
    const float* __restrict__ wk1, const float* __restrict__ wk2,
    const float* __restrict__ wv1, const float* __restrict__ wv2,
    const float* __restrict__ wd0, const float* __restrict__ wd1,
    f16x4* __restrict__ w1pk, f16x4* __restrict__ w1pv,
    _Float16* __restrict__ w2fk, _Float16* __restrict__ w2fv,
    float* __restrict__ g, int* __restrict__ cnt)
{
    const int b = blockIdx.x;
    if (b < 18) {
        int tid = b * TPB + threadIdx.x;   // 4608 exactly
        {
            int p = tid / 2304, rem = tid % 2304;
            int fg = rem >> 6, l = rem & 63;
            int t = fg >> 1, s = fg & 1;
            int kbase = s * 32 + (l >> 4) * 8;
            int m = t * 16 + (l & 15);
            float sig = (m < 128) ? SIG_SS : (m < 192) ? SIG_UU
                      : (m < 256) ? SIG_SU : SIG_US;
            const float* W2 = p ? wv2 : wk2;
            _Float16* dst = (p ? w2fv : w2fk) + (size_t)(fg * 64 + l) * 8;
#pragma unroll
            for (int jj = 0; jj < 8; ++jj)
                dst[jj] = (_Float16)(W2[(size_t)(kbase + jj) * 288 + m] * sig);
        }
        // W1 MFMA A-frag pack (r25): 16x16x16 f16 A[m][k], m=lane&15, k=4q+i.
        if (tid < 256) {
            int t = tid >> 6, ll = tid & 63;
            int qq = ll >> 4, nn = ll & 15;
            int hh = 16 * t + nn;
            f16x4 pk, pv;
#pragma unroll
            for (int i2 = 0; i2 < 4; ++i2) {
                pk[i2] = (_Float16)(wk1[(4 * qq + i2) * 64 + hh] * 0.25f);
                pv[i2] = (_Float16)(wv1[(4 * qq + i2) * 64 + hh] * 0.25f);
            }
            w1pk[tid] = pk;
            w1pv[tid] = pv;
        }
    } else if (b < 136) {
        // ---- per-node g = Wd-folded q (r12-verified) ----
        int n = (b - 18) * TPB + threadIdx.x;
        if (n >= NN) return;
        const float* xr = x + (size_t)n * 40;
        float* o = g + (size_t)n * 20;
        float q0[8];
#pragma unroll
        for (int bb = 0; bb < 8; ++bb) {
            float acc = 0.f;
#pragma unroll
            for (int a = 0; a < 16; ++a) acc += xr[a] * wq0[a * 8 + bb];
            q0[bb] = acc * 0.25f;
        }
#pragma unroll
        for (int bb = 0; bb < 8; ++bb) {
            float acc = 0.f;
#pragma unroll
            for (int a = 0; a < 8; ++a) acc += q0[a] * wd0[a * 8 + bb];
            o[bb] = acc * D0S;
        }
        float q1[4][3];
#pragma unroll
        for (int bb = 0; bb < 4; ++bb)
#pragma unroll
            for (int c = 0; c < 3; ++c) {
                float acc = 0.f;
#pragma unroll
                for (int a = 0; a < 8; ++a) acc += xr[16 + a * 3 + c] * wq1[a * 4 + bb];
                q1[bb][c] = acc * INV_SQRT8;
            }
#pragma unroll
        for (int bb = 0; bb < 4; ++bb)
#pragma unroll
            for (int c = 0; c < 3; ++c) {
                float acc = 0.f;
#pragma unroll
                for (int a = 0; a < 4; ++a) acc += q1[a][c] * wd1[a * 4 + bb];
                o[8 + bb * 3 + c] = acc * D1S;
            }
    } else {
        // ---- edge histogram (cnt pre-zeroed by memset) ----
        int e = (b - 136) * TPB + threadIdx.x;   // 1875 blocks, exact
        atomicAdd(cnt + ei[NE + e], 1);
    }
}

// ---------- parallel order-free scan: block-local prefix + atomic base ----------
__global__ __launch_bounds__(TPB) void scan_blk(const int* __restrict__ cnt,
                                                int* __restrict__ offs,
                                                int* __restrict__ base)
{
    __shared__ int sdata[TPB];
    __shared__ int bbase;
    const int t = threadIdx.x;
    const int idx = blockIdx.x * TPB + t;
    const int v = (idx < NN) ? cnt[idx] : 0;
    sdata[t] = v;
    __syncthreads();
    for (int off = 1; off < TPB; off <<= 1) {
        int u = (t >= off) ? sdata[t - off] : 0;
        __syncthreads();
        sdata[t] += u;
        __syncthreads();
    }
    if (t == TPB - 1) bbase = atomicAdd(base, sdata[TPB - 1]);
    __syncthreads();
    if (idx < NN) offs[idx] = bbase + sdata[t] - v;   // exclusive within block
}

// tile-group GEMM phase: dump NT tiles (local cols) into sh_R
#define GEMM_PHASE(W2F, B0_, B1_, T0, NT) do {                                 \
    _Pragma("unroll")                                                          \
    for (int tt = 0; tt < (NT); ++tt) {                                        \
        const int t_ = (T0) + tt;                                              \
        f16x8 A0 = (W2F)[(t_ * 2 + 0) * 64 + l];                               \
        f16x8 A1 = (W2F)[(t_ * 2 + 1) * 64 + l];                               \
        f32x4 acc = f32x4{0.f, 0.f, 0.f, 0.f};                                 \
        acc = __builtin_amdgcn_mfma_f32_16x16x32_f16(A0, B0_, acc, 0, 0, 0);   \
        acc = __builtin_amdgcn_mfma_f32_16x16x32_f16(A1, B1_, acc, 0, 0, 0);   \
        f16x4 rv = {(_Float16)acc[0], (_Float16)acc[1],                        \
                    (_Float16)acc[2], (_Float16)acc[3]};                       \
        *(f16x4*)&sh_R[n][tt * 16 + 4 * q] = rv;                               \
    }                                                                          \
} while (0)

// ---------- fused k+v edge kernel: phase-split GEMM (r26) ----------
// r25b: MFMA h-MLP got edge to ~150us; occ 42% == issue rate (waves
// issue-saturated), LDS 9728B binds at 16 blk/CU (50% ceiling). r26: the 4
// P-regions (ss/uu/su/us = tiles 0-7/8-11/12-15/16-17) are ADDITIVE -> run
// the GEMM in 4 phases through a reused 16x136 buffer (4352B), accumulating
// each region's partials into regs right after its dump. Same MFMA/loads;
// P0/P1 live across phases (+20 regs, ~84 <= 124 cap). LDS -> ~4.4KB:
// blocks/CU 16 -> 32, waves now reg-bound ~20-24/CU (62-75% ceiling).
// Falsifiers: WRITE>150MB (spill) or occ up w/o dur down -> revert r25b,
// go attack aux kernels.
__global__ __launch_bounds__(ETPB, 2) void edge_fused(
    const float* __restrict__ x, const int* __restrict__ ei,
    const float* __restrict__ eattr, const float* __restrict__ emb,
    const float* __restrict__ el,
    const f16x4* __restrict__ w1pk, const f16x8* __restrict__ w2fk,
    const f16x4* __restrict__ w1pv, const f16x8* __restrict__ w2fv,
    const float* __restrict__ gn, const int* __restrict__ offs,
    int* __restrict__ c2, float* __restrict__ Z,
    float* __restrict__ evs, _Float16* __restrict__ vsc)
{
    __shared__ __align__(16) _Float16 sh_R[16][136];  // h stage + phase dumps (4352 B)

    const int l = threadIdx.x;            // single wave
    const int q = l >> 4, n = l & 15;
    const int e = blockIdx.x * 16 + n;
    const int i = ei[e];
    const int j = ei[NE + e];
    const float4 ea = *(const float4*)(eattr + (size_t)e * 4);
    const float y0 = ea.x, y1x = ea.y, y1y = ea.z, y1z = ea.w;
    const float len = el[e];

    // in-kernel rank (CSR slot); latency hides under h phase
    int pe0 = 0;
    if (l < 16) pe0 = offs[j] + atomicAdd(c2 + j, 1);

    // ---- h-MLP via MFMA; B fragments land register-resident (r25) ----
    f16x8 Bk0, Bk1, Bv0, Bv1;
    {
        f16x4 Bemb;
        {
            float4 v = *(const float4*)(emb + (size_t)e * 16 + 4 * q);
            Bemb = f16x4{(_Float16)v.x, (_Float16)v.y,
                         (_Float16)v.z, (_Float16)v.w};
        }
        const f32x4 zero = f32x4{0.f, 0.f, 0.f, 0.f};
#pragma unroll
        for (int t = 0; t < 4; ++t) {
            f32x4 acc = __builtin_amdgcn_mfma_f32_16x16x16f16(
                w1pk[t * 64 + l], Bemb, zero, 0, 0, 0);
            f16x4 h4;
#pragma unroll
            for (int r = 0; r < 4; ++r) {
                const float z = acc[r];
                h4[r] = (_Float16)(z * __builtin_amdgcn_rcpf(1.f + __expf(-z)));
            }
            *(f16x4*)&sh_R[n][t * 16 + 4 * q] = h4;
        }
        WBAR();
        Bk0 = *(const f16x8*)&sh_R[n][8 * q];        // k in {8q..8q+7}
        Bk1 = *(const f16x8*)&sh_R[n][32 + 8 * q];   // k in {32+8q..+7}
        WBAR();   // Bk reads precede h_v overwrite (in-order DS)
#pragma unroll
        for (int t = 0; t < 4; ++t) {
            f32x4 acc = __builtin_amdgcn_mfma_f32_16x16x16f16(
                w1pv[t * 64 + l], Bemb, zero, 0, 0, 0);
            f16x4 h4;
#pragma unroll
            for (int r = 0; r < 4; ++r) {
                const float z = acc[r];
                h4[r] = (_Float16)(z * __builtin_amdgcn_rcpf(1.f + __expf(-z)));
            }
            *(f16x4*)&sh_R[n][t * 16 + 4 * q] = h4;
        }
        WBAR();
        Bv0 = *(const f16x8*)&sh_R[n][8 * q];
        Bv1 = *(const f16x8*)&sh_R[n][32 + 8 * q];
    }

    // ---- this thread's x-slice: s-channels [4q,4q+4), u-channels [2q,2q+2) ----
    float xs[4];
    float xu[2][3];
    {
        const float* xb = x + (size_t)i * 40;
        float4 s4 = *(const float4*)(xb + 4 * q);
        xs[0] = s4.x; xs[1] = s4.y; xs[2] = s4.z; xs[3] = s4.w;
        const float* ub = xb + 16 + 6 * q;
        float2 u0 = *(const float2*)(ub);
        float2 u1 = *(const float2*)(ub + 2);
        float2 u2 = *(const float2*)(ub + 4);
        xu[0][0] = u0.x; xu[0][1] = u0.y; xu[0][2] = u1.x;
        xu[1][0] = u1.y; xu[1][1] = u2.x; xu[1][2] = u2.y;
    }

    // region-partial accumulators (local cols in the reused buffer)
    auto P_SS = [&](float P0[8]) {       // tiles 0-7: local (4q+d)*8
#pragma unroll
        for (int b = 0; b < 8; ++b) P0[b] = 0.f;
#pragma unroll
        for (int d = 0; d < 4; ++d) {
            const f16x8 rv = *(const f16x8*)&sh_R[n][(4 * q + d) * 8];
            const float xv = xs[d];
#pragma unroll
            for (int b = 0; b < 8; ++b) P0[b] += xv * (float)rv[b];
        }
#pragma unroll
        for (int b = 0; b < 8; ++b) P0[b] *= y0;
    };
    auto P_UU = [&](float P0[8]) {       // tiles 8-11: local (2q+d)*8
#pragma unroll
        for (int d = 0; d < 2; ++d) {
            const f16x8 rv = *(const f16x8*)&sh_R[n][(2 * q + d) * 8];
            const float xy = xu[d][0] * y1x + xu[d][1] * y1y + xu[d][2] * y1z;
#pragma unroll
            for (int b = 0; b < 8; ++b) P0[b] += xy * (float)rv[b];
        }
    };
    auto P_SU = [&](float P1[4][3]) {    // tiles 12-15: local (4q+d)*4
        float su[4] = {0.f, 0.f, 0.f, 0.f};
#pragma unroll
        for (int d = 0; d < 4; ++d) {
            const f16x4 rv = *(const f16x4*)&sh_R[n][(4 * q + d) * 4];
            const float xv = xs[d];
#pragma unroll
            for (int b = 0; b < 4; ++b) su[b] += xv * (float)rv[b];
        }
#pragma unroll
        for (int b = 0; b < 4; ++b) {
            P1[b][0] = su[b] * y1x;
            P1[b][1] = su[b] * y1y;
            P1[b][2] = su[b] * y1z;
        }
    };
    auto P_US = [&](float P1[4][3]) {    // tiles 16-17: local (2q+d)*4
#pragma unroll
        for (int d = 0; d < 2; ++d) {
            const f16x4 rv = *(const f16x4*)&sh_R[n][(2 * q + d) * 4];
#pragma unroll
            for (int b = 0; b < 4; ++b) {
                const float wv = y0 * (float)rv[b];
                P1[b][0] += xu[d][0] * wv;
                P1[b][1] += xu[d][1] * wv;
                P1[b][2] += xu[d][2] * wv;
            }
        }
    };

    // ================= K path: 4 phases + score =================
    {
        float P0[8], P1[4][3];
        GEMM_PHASE(w2fk, Bk0, Bk1, 0, 8);
        WBAR();
        P_SS(P0);
        WBAR();
        GEMM_PHASE(w2fk, Bk0, Bk1, 8, 4);
        WBAR();
        P_UU(P0);
        WBAR();
        GEMM_PHASE(w2fk, Bk0, Bk1, 12, 4);
        WBAR();
        P_SU(P1);
        WBAR();
        GEMM_PHASE(w2fk, Bk0, Bk1, 16, 2);
        WBAR();
        P_US(P1);

        const float* gj = gn + (size_t)j * 20;
        float pd = 0.f;
        {
            float4 ga = *(const float4*)(gj);
            float4 gb = *(const float4*)(gj + 4);
            pd += P0[0] * ga.x + P0[1] * ga.y + P0[2] * ga.z + P0[3] * ga.w;
            pd += P0[4] * gb.x + P0[5] * gb.y + P0[6] * gb.z + P0[7] * gb.w;
        }
        {
            float4 ga = *(const float4*)(gj + 8);
            float4 gb = *(const float4*)(gj + 12);
            float4 gc = *(const float4*)(gj + 16);
            pd += P1[0][0] * ga.x + P1[0][1] * ga.y + P1[0][2] * ga.z
                + P1[1][0] * ga.w;
            pd += P1[1][1] * gb.x + P1[1][2] * gb.y + P1[2][0] * gb.z
                + P1[2][1] * gb.w;
            pd += P1[2][2] * gc.x + P1[3][0] * gc.y + P1[3][1] * gc.z
                + P1[3][2] * gc.w;
        }
        pd += __shfl_xor(pd, 16);
        pd += __shfl_xor(pd, 32);
        if (l < 16) {
            const float tt = 10.f * (1.f - len / 3.15f);
            float cut = 0.f;
            if (tt > 0.f) cut = __expf(-1.f / fmaxf(tt, 1e-6f));
            const float ev = cut * __expf(pd);
            evs[pe0] = ev;
            atomicAdd(Z + j, ev);
        }
    }
    WBAR();   // K-path partial reads precede V-phase dumps (in-order DS)

    // ================= V path: 4 phases + record store =================
    {
        float P0[8], P1[4][3];
        GEMM_PHASE(w2fv, Bv0, Bv1, 0, 8);
        WBAR();
        P_SS(P0);
        WBAR();
        GEMM_PHASE(w2fv, Bv0, Bv1, 8, 4);
        WBAR();
        P_UU(P0);
        WBAR();
        GEMM_PHASE(w2fv, Bv0, Bv1, 12, 4);
        WBAR();
        P_SU(P1);
        WBAR();
        GEMM_PHASE(w2fv, Bv0, Bv1, 16, 2);
        WBAR();
        P_US(P1);

#pragma unroll
        for (int b = 0; b < 8; ++b) {
            P0[b] += __shfl_xor(P0[b], 16);
            P0[b] += __shfl_xor(P0[b], 32);
        }
#pragma unroll
        for (int b = 0; b < 4; ++b)
#pragma unroll
            for (int c = 0; c < 3; ++c) {
                P1[b][c] += __shfl_xor(P1[b][c], 16);
                P1[b][c] += __shfl_xor(P1[b][c], 32);
            }
        if (l < 16) {
            _Float16* rec = vsc + (size_t)pe0 * 20;   // 40B records
            f16x4 o0 = {(_Float16)P0[0], (_Float16)P0[1],
                        (_Float16)P0[2], (_Float16)P0[3]};
            f16x4 o1 = {(_Float16)P0[4], (_Float16)P0[5],
                        (_Float16)P0[6], (_Float16)P0[7]};
            f16x4 o2 = {(_Float16)P1[0][0], (_Float16)P1[0][1],
                        (_Float16)P1[0][2], (_Float16)P1[1][0]};
            f16x4 o3 = {(_Float16)P1[1][1], (_Float16)P1[1][2],
                        (_Float16)P1[2][0], (_Float16)P1[2][1]};
            f16x4 o4 = {(_Float16)P1[2][2], (_Float16)P1[3][0],
                        (_Float16)P1[3][1], (_Float16)P1[3][2]};
            *(f16x4*)&rec[0]  = o0;
            *(f16x4*)&rec[4]  = o1;
            *(f16x4*)&rec[8]  = o2;
            *(f16x4*)&rec[12] = o3;
            *(f16x4*)&rec[16] = o4;
        }
    }
}

// ---------- node gather: Z precomputed; single weighted pass, zero atomics ----------
__global__ __launch_bounds__(TPB) void node_gather(
    const int* __restrict__ offs, const int* __restrict__ cntp,
    const float* __restrict__ Z,
    const float* __restrict__ evs, const _Float16* __restrict__ vsc,
    float* __restrict__ out)
{
    const int wv = threadIdx.x >> 6, lane = threadIdx.x & 63;
    const int j = blockIdx.x * 4 + wv;
    if (j >= NN) return;
    const int o0 = offs[j], cnt = cntp[j];
    const float zz = Z[j];
    const float invZ = (zz > 0.f) ? (1.f / zz) : 0.f;

    const int g = lane / 20, c = lane % 20;
    float acc = 0.f;
    if (g < 3) {
        for (int t = g; t < cnt; t += 3) {
            const float ev = evs[o0 + t];
            const float wgt = sqrtf(fmaxf(ev * invZ, 0.f));
            acc += wgt * (float)vsc[(size_t)(o0 + t) * 20 + c];
        }
    }
    const float a1 = __shfl(acc, lane + 20);
    const float a2 = __shfl(acc, lane + 40);
    if (lane < 20) out[(size_t)j * 20 + lane] = acc + a1 + a2;
}

extern "C" void kernel_launch(void* const* d_in, const int* in_sizes, int n_in,
                              void* d_out, int out_size, void* d_ws, size_t ws_size,
                              hipStream_t stream)
{
    const float* x     = (const float*)d_in[0];
    const int*   eidx  = (const int*)d_in[1];
    const float* eattr = (const float*)d_in[2];
    const float* emb   = (const float*)d_in[3];
    const float* elen  = (const float*)d_in[4];
    const float* wq0   = (const float*)d_in[5];
    const float* wq1   = (const float*)d_in[6];
    const float* wk1   = (const float*)d_in[7];
    const float* wk2   = (const float*)d_in[8];
    const float* wv1   = (const float*)d_in[9];
    const float* wv2   = (const float*)d_in[10];
    const float* wd0   = (const float*)d_in[11];
    const float* wd1   = (const float*)d_in[12];

    float* ws  = (float*)d_ws;
    float* out = (float*)d_out;

    f16x4* w1pk = (f16x4*)(ws + NW1K_OFF);
    f16x4* w1pv = (f16x4*)(ws + NW1V_OFF);
    _Float16* w2fk = (_Float16*)(ws + NW2K_OFF);
    _Float16* w2fv = (_Float16*)(ws + NW2V_OFF);
    int* cnt  = (int*)(ws + NCNT_OFF);
    int* c2   = (int*)(ws + NC2_OFF);
    float* Z  = ws + NZ_OFF;
    int* base = (int*)(ws + NBASE_OFF);
    int* offs = (int*)(ws + NOFF_OFF);
    float* evs = ws + NEVS_OFF;
    _Float16* vsc = (_Float16*)(ws + NVSC_OFF);

    // zero cnt + c2 + Z + base (contiguous) in one memset
    hipMemsetAsync(cnt, 0, (3 * NN + 8) * sizeof(int), stream);

    // prep: weights + g + histogram (1875 hist blocks)
    prep_all<<<136 + NE / TPB, TPB, 0, stream>>>(
        x, eidx, wq0, wq1, wk1, wk2, wv1, wv2, wd0, wd1,
        w1pk, w1pv, w2fk, w2fv, ws + NG_OFF, cnt);

    scan_blk<<<(NN + TPB - 1) / TPB, TPB, 0, stream>>>(cnt, offs, base);

    edge_fused<<<NE / 16, ETPB, 0, stream>>>(
        x, eidx, eattr, emb, elen,
        w1pk, (const f16x8*)w2fk, w1pv, (const f16x8*)w2fv,
        ws + NG_OFF, offs, c2, Z, evs, vsc);

    node_gather<<<(NN + 3) / 4, TPB, 0, stream>>>(offs, cnt, Z, evs, vsc, out);
}